// Round 10
// baseline (484.657 us; speedup 1.0000x reference)
//
#include <hip/hip_runtime.h>
#include <stdint.h>
#include <math.h>

// ---------------------------------------------------------------------------
// EncoderLayer. I/O fp32 (mask int32). Internal bf16 MFMA, fp32 accum.
// R10: GEMM BK=64 (two 32-col LDS halves, half the barrier rounds),
// attn alpha-skip (wave-uniform), fc1 GELU via exp2. Rest = R9 (passed).
// ---------------------------------------------------------------------------

typedef uint16_t u16;
typedef unsigned long long u64;
typedef __attribute__((ext_vector_type(8))) short short8;   // 8 x bf16
typedef __attribute__((ext_vector_type(4))) float f32x4;

#define S_LEN 2048
#define DM 1024

#define GLOAD_LDS16(g, l)                                                      \
  __builtin_amdgcn_global_load_lds(                                            \
      (const __attribute__((address_space(1))) void*)(g),                      \
      (__attribute__((address_space(3))) void*)(l), 16, 0, 0)

__device__ __forceinline__ float bf2f(u16 h) {
  union { uint32_t u; float f; } x;
  x.u = ((uint32_t)h) << 16;
  return x.f;
}
__device__ __forceinline__ u16 f2bf(float f) {
  union { float f; uint32_t u; } x;
  x.f = f;
  uint32_t r = (x.u + 0x7fffu + ((x.u >> 16) & 1u)) >> 16;  // RNE
  return (u16)r;
}
__device__ __forceinline__ u16 f2bf_fast(float f) {  // round-half-up
  union { float f; uint32_t u; } x;
  x.f = f;
  return (u16)((x.u + 0x8000u) >> 16);
}
__device__ __forceinline__ float gelu_fast(float x) {
  // tanh-form GELU via exp2: x*e/(1+e), e = exp2(2*log2e*0.7978845608*(x+0.044715x^3))
  float x3 = x * x * x;
  float z = 2.302118131f * fmaf(0.044715f, x3, x);
  float e = __builtin_amdgcn_exp2f(z);
  return x * e / (1.0f + e);
}

union U8 { uint4 u; u16 s[8]; };
union U4 { uint2 u; u16 s[4]; };

// ---------------------------------------------------------------------------
__global__ __launch_bounds__(256) void cvt_k(const float* __restrict__ in,
                                             u16* __restrict__ out, int n) {
  int i = (blockIdx.x * 256 + threadIdx.x) * 4;
  if (i >= n) return;
  float4 v = *(const float4*)(in + i);
  U4 o;
  o.s[0] = f2bf(v.x); o.s[1] = f2bf(v.y); o.s[2] = f2bf(v.z); o.s[3] = f2bf(v.w);
  *(uint2*)(out + i) = o.u;
}

// ---------------------------------------------------------------------------
__global__ __launch_bounds__(256) void mb_k(const int* __restrict__ mask,
                                            u16* __restrict__ mb) {
  int tid = blockIdx.x * 256 + threadIdx.x;
  const int* src = mask + (size_t)tid * 16;
  uint32_t b = 0;
#pragma unroll
  for (int q = 0; q < 4; q++) {
    int4 m = *(const int4*)(src + q * 4);
    b |= (m.x != 0 ? 1u : 0u) << (q * 4 + 0);
    b |= (m.y != 0 ? 1u : 0u) << (q * 4 + 1);
    b |= (m.z != 0 ? 1u : 0u) << (q * 4 + 2);
    b |= (m.w != 0 ? 1u : 0u) << (q * 4 + 3);
  }
  mb[tid] = (u16)b;
}

// ---------------------------------------------------------------------------
__device__ __forceinline__ void tcvt_body(const float* __restrict__ in,
                                          u16* __restrict__ out, int R, int C) {
  __shared__ u16 tile[64][72];
  int c0 = blockIdx.x * 64, r0 = blockIdx.y * 64;
  int t = threadIdx.x;
  int r = t & 63, seg = t >> 6;
  const float* src = in + (size_t)(r0 + r) * C + c0 + seg * 16;
#pragma unroll
  for (int q = 0; q < 4; q++) {
    float4 v = *(const float4*)(src + q * 4);
    tile[r][seg * 16 + q * 4 + 0] = f2bf(v.x);
    tile[r][seg * 16 + q * 4 + 1] = f2bf(v.y);
    tile[r][seg * 16 + q * 4 + 2] = f2bf(v.z);
    tile[r][seg * 16 + q * 4 + 3] = f2bf(v.w);
  }
  __syncthreads();
  U8 v0, v1;
#pragma unroll
  for (int i = 0; i < 8; i++) v0.s[i] = tile[seg * 16 + i][r];
#pragma unroll
  for (int i = 0; i < 8; i++) v1.s[i] = tile[seg * 16 + 8 + i][r];
  u16* dst = out + (size_t)(c0 + r) * R + r0 + seg * 16;
  *(uint4*)dst = v0.u;
  *(uint4*)(dst + 8) = v1.u;
}

__global__ __launch_bounds__(256) void transpose_cvt_k(const float* __restrict__ in,
                                                       u16* __restrict__ out,
                                                       int R, int C) {
  tcvt_body(in, out, R, C);
}

__global__ __launch_bounds__(256) void transpose_cvt3_k(const float* __restrict__ i0,
                                                        const float* __restrict__ i1,
                                                        const float* __restrict__ i2,
                                                        u16* __restrict__ o0,
                                                        u16* __restrict__ o1,
                                                        u16* __restrict__ o2) {
  int z = blockIdx.z;
  const float* in = (z == 0) ? i0 : (z == 1) ? i1 : i2;
  u16* out = (z == 0) ? o0 : (z == 1) ? o1 : o2;
  tcvt_body(in, out, 1024, 1024);
}

// ---------------------------------------------------------------------------
__global__ __launch_bounds__(256) void vtrans_k(const u16* __restrict__ V,
                                                u16* __restrict__ VT) {
  __shared__ u16 tile[64][72];
  int bx = blockIdx.x, bh = blockIdx.y;
  int b = bh >> 4, h = bh & 15;
  int t = threadIdx.x, r = t & 63, seg = t >> 6;
  const u16* src = V + (size_t)(b * S_LEN + bx * 64 + r) * DM + h * 64 + seg * 16;
  *(uint4*)&tile[r][seg * 16] = *(const uint4*)src;
  *(uint4*)&tile[r][seg * 16 + 8] = *(const uint4*)(src + 8);
  __syncthreads();
  U8 v0, v1;
#pragma unroll
  for (int i = 0; i < 8; i++) v0.s[i] = tile[seg * 16 + i][r];
#pragma unroll
  for (int i = 0; i < 8; i++) v1.s[i] = tile[seg * 16 + 8 + i][r];
  u16* dst = VT + ((size_t)bh * 64 + r) * S_LEN + bx * 64 + seg * 16;
  *(uint4*)dst = v0.u;
  *(uint4*)(dst + 8) = v1.u;
}

// ---------------------------------------------------------------------------
// bf16 GEMM, BK=64 via two 32-col LDS halves (one barrier pair / 64 K-steps).
// BM in {128,64}. EPI: 0=+bias ; 2=+bias,GELU. MXS=1: M-tile in blockIdx.x.
// K must be a multiple of 64.
// ---------------------------------------------------------------------------
template <int BM, int EPI, int MXS>
__global__ __launch_bounds__(256) void gemm_bt(const u16* __restrict__ A,
                                               const u16* __restrict__ Bt,
                                               u16* __restrict__ C,
                                               const float* __restrict__ bias,
                                               int M, int N, int K) {
  constexpr int MI = BM / 32;
  constexpr int RPW = BM / 4;
  __shared__ u16 As[2][BM * 32];
  __shared__ u16 Bs[2][128 * 32];
  int t = threadIdx.x;
  int wid = t >> 6, lane = t & 63;
  int g = lane >> 4, li = lane & 15;
  int bx = MXS ? blockIdx.y : blockIdx.x;
  int by = MXS ? blockIdx.x : blockIdx.y;
  int wr = (wid >> 1) * (BM / 2), wc = (wid & 1) * 64;

  const u16* a0 = A + (size_t)(by * BM + wid * RPW + (lane >> 2)) * K + (lane & 3) * 8;
  const u16* b0 = Bt + (size_t)(bx * 128 + wid * 32 + (lane >> 2)) * K + (lane & 3) * 8;
  u16* lA0 = &As[0][wid * RPW * 32];
  u16* lA1 = &As[1][wid * RPW * 32];
  u16* lB0 = &Bs[0][wid * 1024];
  u16* lB1 = &Bs[1][wid * 1024];

  f32x4 acc[MI][4];
#pragma unroll
  for (int i = 0; i < MI; i++)
#pragma unroll
    for (int j = 0; j < 4; j++) acc[i][j] = (f32x4){0.f, 0.f, 0.f, 0.f};

  for (int k0 = 0; k0 < K; k0 += 64) {
    GLOAD_LDS16(a0 + k0, lA0);
    if (BM == 128) GLOAD_LDS16(a0 + (size_t)16 * K + k0, lA0 + 512);
    GLOAD_LDS16(b0 + k0, lB0);
    GLOAD_LDS16(b0 + (size_t)16 * K + k0, lB0 + 512);
    GLOAD_LDS16(a0 + k0 + 32, lA1);
    if (BM == 128) GLOAD_LDS16(a0 + (size_t)16 * K + k0 + 32, lA1 + 512);
    GLOAD_LDS16(b0 + k0 + 32, lB1);
    GLOAD_LDS16(b0 + (size_t)16 * K + k0 + 32, lB1 + 512);
    __syncthreads();
#pragma unroll
    for (int h = 0; h < 2; h++) {
      short8 af[MI], bfv[4];
#pragma unroll
      for (int i = 0; i < MI; i++)
        af[i] = *(const short8*)&As[h][(wr + i * 16 + li) * 32 + g * 8];
#pragma unroll
      for (int i = 0; i < 4; i++)
        bfv[i] = *(const short8*)&Bs[h][(wc + i * 16 + li) * 32 + g * 8];
#pragma unroll
      for (int mi = 0; mi < MI; mi++)
#pragma unroll
        for (int ni = 0; ni < 4; ni++)
          acc[mi][ni] = __builtin_amdgcn_mfma_f32_16x16x32_bf16(
              af[mi], bfv[ni], acc[mi][ni], 0, 0, 0);
    }
    __syncthreads();
  }

#pragma unroll
  for (int ni = 0; ni < 4; ni++) {
    int col = bx * 128 + wc + ni * 16 + li;
    float bv = bias[col];
#pragma unroll
    for (int mi = 0; mi < MI; mi++) {
#pragma unroll
      for (int r = 0; r < 4; r++) {
        int row = by * BM + wr + mi * 16 + g * 4 + r;
        float v = acc[mi][ni][r] + bv;
        if (EPI == 2) v = gelu_fast(v);
        C[(size_t)row * N + col] = f2bf(v);
      }
    }
  }
}

// ---------------------------------------------------------------------------
// Fused QKV projection (BK=64): grid (32, 8, 3); x=M-tile, y=N-tile, z=weight.
// ---------------------------------------------------------------------------
__global__ __launch_bounds__(256) void qkv_gemm(const u16* __restrict__ A,
                                                const u16* __restrict__ WTq,
                                                const u16* __restrict__ WTk,
                                                const u16* __restrict__ WTv,
                                                u16* __restrict__ Cq,
                                                u16* __restrict__ Ck,
                                                u16* __restrict__ Cv,
                                                const float* __restrict__ bq,
                                                const float* __restrict__ bk,
                                                const float* __restrict__ bv,
                                                const float* __restrict__ tw) {
  const int K = 1024, N = 1024;
  __shared__ u16 As[2][128 * 32];
  __shared__ u16 Bs[2][128 * 32];
  int t = threadIdx.x;
  int wid = t >> 6, lane = t & 63;
  int g = lane >> 4, li = lane & 15;
  int by = blockIdx.x, bx = blockIdx.y, z = blockIdx.z;
  int wr = (wid >> 1) * 64, wc = (wid & 1) * 64;

  const u16* Bt = (z == 0) ? WTq : (z == 1) ? WTk : WTv;
  u16* C = (z == 0) ? Cq : (z == 1) ? Ck : Cv;
  const float* bias = (z == 0) ? bq : (z == 1) ? bk : bv;

  const u16* a0 = A + (size_t)(by * 128 + wid * 32 + (lane >> 2)) * K + (lane & 3) * 8;
  const u16* b0 = Bt + (size_t)(bx * 128 + wid * 32 + (lane >> 2)) * K + (lane & 3) * 8;
  u16* lA0 = &As[0][wid * 1024];
  u16* lA1 = &As[1][wid * 1024];
  u16* lB0 = &Bs[0][wid * 1024];
  u16* lB1 = &Bs[1][wid * 1024];

  f32x4 acc[4][4];
#pragma unroll
  for (int i = 0; i < 4; i++)
#pragma unroll
    for (int j = 0; j < 4; j++) acc[i][j] = (f32x4){0.f, 0.f, 0.f, 0.f};

  for (int k0 = 0; k0 < K; k0 += 64) {
    GLOAD_LDS16(a0 + k0, lA0);
    GLOAD_LDS16(a0 + (size_t)16 * K + k0, lA0 + 512);
    GLOAD_LDS16(b0 + k0, lB0);
    GLOAD_LDS16(b0 + (size_t)16 * K + k0, lB0 + 512);
    GLOAD_LDS16(a0 + k0 + 32, lA1);
    GLOAD_LDS16(a0 + (size_t)16 * K + k0 + 32, lA1 + 512);
    GLOAD_LDS16(b0 + k0 + 32, lB1);
    GLOAD_LDS16(b0 + (size_t)16 * K + k0 + 32, lB1 + 512);
    __syncthreads();
#pragma unroll
    for (int h = 0; h < 2; h++) {
      short8 af[4], bfv[4];
#pragma unroll
      for (int i = 0; i < 4; i++)
        af[i] = *(const short8*)&As[h][(wr + i * 16 + li) * 32 + g * 8];
#pragma unroll
      for (int i = 0; i < 4; i++)
        bfv[i] = *(const short8*)&Bs[h][(wc + i * 16 + li) * 32 + g * 8];
#pragma unroll
      for (int mi = 0; mi < 4; mi++)
#pragma unroll
        for (int ni = 0; ni < 4; ni++)
          acc[mi][ni] = __builtin_amdgcn_mfma_f32_16x16x32_bf16(
              af[mi], bfv[ni], acc[mi][ni], 0, 0, 0);
    }
    __syncthreads();
  }

#pragma unroll
  for (int ni = 0; ni < 4; ni++) {
    int col = bx * 128 + wc + ni * 16 + li;
    float bvv = bias[col];
    if (z == 0) bvv += tw[col];
#pragma unroll
    for (int mi = 0; mi < 4; mi++) {
#pragma unroll
      for (int r = 0; r < 4; r++) {
        int row = by * 128 + wr + mi * 16 + g * 4 + r;
        C[(size_t)row * N + col] = f2bf(acc[mi][ni][r] + bvv);
      }
    }
  }
}

// ---------------------------------------------------------------------------
// Flash attention. grid 1024, 256 thr. bh in low 5 bits (XCD locality).
// exp2-domain softmax; deferred l-reduction; wave-private Ps (no s_barrier);
// alpha rescale skipped when the running max didn't move (wave-uniform).
// ---------------------------------------------------------------------------
__global__ __launch_bounds__(256) void attn_k(const u16* __restrict__ Q,
                                              const u16* __restrict__ Kp,
                                              const u16* __restrict__ VT,
                                              u16* __restrict__ CTX,
                                              const u16* __restrict__ mb,
                                              const float* __restrict__ gateW,
                                              const float* __restrict__ gateb,
                                              const float* __restrict__ temp) {
  __shared__ u16 Qs[64][72];
  __shared__ u16 Ks[64][72];
  __shared__ u16 Vs[64][72];
  __shared__ u16 Ps[4][16][72];
  __shared__ float gate_s[64];

  int blk = blockIdx.x;
  int bh = blk & 31, qt = blk >> 5;
  int b = bh >> 4, h = bh & 15;
  int t = threadIdx.x, wid = t >> 6, lane = t & 63;
  int g = lane >> 4, li = lane & 15;
  int sq0 = qt * 64;

  const u16* Qb  = Q + ((size_t)b * S_LEN) * DM + h * 64;
  const u16* Kb  = Kp + ((size_t)b * S_LEN) * DM + h * 64;
  const u16* VTb = VT + ((size_t)(b * 16 + h) * 64) * S_LEN;

  {
    int r = t >> 2, cs = (t & 3) * 16;
    const u16* src = Qb + (size_t)(sq0 + r) * DM + cs;
    *(uint4*)&Qs[r][cs] = *(const uint4*)src;
    *(uint4*)&Qs[r][cs + 8] = *(const uint4*)(src + 8);
  }
  __syncthreads();
  if (t < 64) {
    float acc = gateb[0];
#pragma unroll
    for (int d = 0; d < 64; d++) acc += bf2f(Qs[t][d]) * gateW[d];
    gate_s[t] = 1.f / (1.f + __expf(-acc));
  }
  __syncthreads();

  const float LOG2E = 1.4426950408889634f;
  float invt2 = LOG2E / temp[0];
  const float NEG2 = -1.0e9f * 1.4426950408889634f;
  short8 qf0 = *(const short8*)&Qs[wid * 16 + li][g * 8];
  short8 qf1 = *(const short8*)&Qs[wid * 16 + li][32 + g * 8];
  float gqs[4], ng[4];
  int sq[4];
#pragma unroll
  for (int r = 0; r < 4; r++) {
    float gq = gate_s[wid * 16 + g * 4 + r];
    gqs[r] = gq * invt2;
    ng[r] = NEG2 * gq;
    sq[r] = sq0 + wid * 16 + g * 4 + r;
  }

  float m_i[4], psl[4];
  f32x4 o[4];
#pragma unroll
  for (int r = 0; r < 4; r++) { m_i[r] = -1e30f; psl[r] = 0.f; }
#pragma unroll
  for (int n = 0; n < 4; n++) o[n] = (f32x4){0.f, 0.f, 0.f, 0.f};

  for (int kt = 0; kt < 32; kt++) {
    __syncthreads();
    {
      int r = t >> 2, cs = (t & 3) * 16;
      const u16* srcK = Kb + (size_t)(kt * 64 + r) * DM + cs;
      *(uint4*)&Ks[r][cs] = *(const uint4*)srcK;
      *(uint4*)&Ks[r][cs + 8] = *(const uint4*)(srcK + 8);
      const u16* srcV = VTb + (size_t)r * S_LEN + kt * 64 + cs;
      *(uint4*)&Vs[r][cs] = *(const uint4*)srcV;
      *(uint4*)&Vs[r][cs + 8] = *(const uint4*)(srcV + 8);
    }
    u64 bits[4];
#pragma unroll
    for (int r = 0; r < 4; r++)
      bits[r] = *(const u64*)(mb + (size_t)sq[r] * 128 + kt * 4);
    __syncthreads();

    f32x4 sc[4];
#pragma unroll
    for (int ni = 0; ni < 4; ni++) {
      sc[ni] = (f32x4){0.f, 0.f, 0.f, 0.f};
      short8 kf0 = *(const short8*)&Ks[ni * 16 + li][g * 8];
      short8 kf1 = *(const short8*)&Ks[ni * 16 + li][32 + g * 8];
      sc[ni] = __builtin_amdgcn_mfma_f32_16x16x32_bf16(qf0, kf0, sc[ni], 0, 0, 0);
      sc[ni] = __builtin_amdgcn_mfma_f32_16x16x32_bf16(qf1, kf1, sc[ni], 0, 0, 0);
    }

    float sval[4][4];
    float rmax[4] = {-1e30f, -1e30f, -1e30f, -1e30f};
    bool allm = ((bits[0] & bits[1] & bits[2] & bits[3]) == ~0ull);
    if (__all(allm)) {
#pragma unroll
      for (int ni = 0; ni < 4; ni++)
#pragma unroll
        for (int r = 0; r < 4; r++) {
          float s = sc[ni][r] * gqs[r];
          sval[ni][r] = s;
          rmax[r] = fmaxf(rmax[r], s);
        }
    } else {
      u64 bs[4];
#pragma unroll
      for (int r = 0; r < 4; r++) bs[r] = bits[r] >> li;
#pragma unroll
      for (int ni = 0; ni < 4; ni++)
#pragma unroll
        for (int r = 0; r < 4; r++) {
          float s = ((bs[r] >> (ni * 16)) & 1ull) ? sc[ni][r] * gqs[r] : ng[r];
          sval[ni][r] = s;
          rmax[r] = fmaxf(rmax[r], s);
        }
    }
#pragma unroll
    for (int off = 1; off < 16; off <<= 1)
#pragma unroll
      for (int r = 0; r < 4; r++)
        rmax[r] = fmaxf(rmax[r], __shfl_xor(rmax[r], off, 64));

    // rescale only when the running max moved (wave-uniform branch)
    bool up = (rmax[0] > m_i[0]) | (rmax[1] > m_i[1]) |
              (rmax[2] > m_i[2]) | (rmax[3] > m_i[3]);
    if (__any(up)) {
      float alpha[4];
#pragma unroll
      for (int r = 0; r < 4; r++) {
        float mnew = fmaxf(m_i[r], rmax[r]);
        alpha[r] = __builtin_amdgcn_exp2f(m_i[r] - mnew);
        m_i[r] = mnew;
      }
#pragma unroll
      for (int r = 0; r < 4; r++) psl[r] *= alpha[r];
#pragma unroll
      for (int n = 0; n < 4; n++)
#pragma unroll
        for (int r = 0; r < 4; r++) o[n][r] *= alpha[r];
    }

    float pp[4] = {0.f, 0.f, 0.f, 0.f};
#pragma unroll
    for (int ni = 0; ni < 4; ni++)
#pragma unroll
      for (int r = 0; r < 4; r++) {
        float p = __builtin_amdgcn_exp2f(sval[ni][r] - m_i[r]);
        pp[r] += p;
        Ps[wid][g * 4 + r][ni * 16 + li] = f2bf_fast(p);
      }
#pragma unroll
    for (int r = 0; r < 4; r++) psl[r] += pp[r];

    __builtin_amdgcn_wave_barrier();  // Ps wave-private: pin order only

    short8 pf0 = *(const short8*)&Ps[wid][li][g * 8];
    short8 pf1 = *(const short8*)&Ps[wid][li][32 + g * 8];
#pragma unroll
    for (int ni = 0; ni < 4; ni++) {
      short8 vf0 = *(const short8*)&Vs[ni * 16 + li][g * 8];
      short8 vf1 = *(const short8*)&Vs[ni * 16 + li][32 + g * 8];
      o[ni] = __builtin_amdgcn_mfma_f32_16x16x32_bf16(pf0, vf0, o[ni], 0, 0, 0);
      o[ni] = __builtin_amdgcn_mfma_f32_16x16x32_bf16(pf1, vf1, o[ni], 0, 0, 0);
    }
  }

  float linv[4];
#pragma unroll
  for (int r = 0; r < 4; r++) {
    float l = psl[r];
#pragma unroll
    for (int off = 1; off < 16; off <<= 1) l += __shfl_xor(l, off, 64);
    linv[r] = 1.f / l;
  }
#pragma unroll
  for (int ni = 0; ni < 4; ni++) {
    int col = h * 64 + ni * 16 + li;
#pragma unroll
    for (int r = 0; r < 4; r++) {
      size_t row = (size_t)b * S_LEN + sq[r];
      CTX[row * DM + col] = f2bf(o[ni][r] * linv[r]);
    }
  }
}

// ---------------------------------------------------------------------------
__device__ __forceinline__ void block_sum2(float& a, float& b, float* red, int t) {
#pragma unroll
  for (int off = 32; off > 0; off >>= 1) {
    a += __shfl_xor(a, off, 64);
    b += __shfl_xor(b, off, 64);
  }
  __syncthreads();
  if ((t & 63) == 0) {
    red[(t >> 6) * 2] = a;
    red[(t >> 6) * 2 + 1] = b;
  }
  __syncthreads();
  a = red[0] + red[2] + red[4] + red[6];
  b = red[1] + red[3] + red[5] + red[7];
}

__global__ __launch_bounds__(256) void ln1_k(const u16* __restrict__ po,
                                             const float* __restrict__ x,
                                             const float* __restrict__ g1,
                                             const float* __restrict__ b1,
                                             const float* __restrict__ g2,
                                             const float* __restrict__ b2,
                                             u16* __restrict__ x1) {
  __shared__ float red[8];
  int row = blockIdx.x, t = threadIdx.x;
  size_t base = (size_t)row * 1024 + t * 4;
  U4 pv; pv.u = *(const uint2*)(po + base);
  float v[4];
#pragma unroll
  for (int i = 0; i < 4; i++) v[i] = bf2f(pv.s[i]);
  float s1 = v[0] + v[1] + v[2] + v[3];
  float s2 = v[0]*v[0] + v[1]*v[1] + v[2]*v[2] + v[3]*v[3];
  block_sum2(s1, s2, red, t);
  float mu = s1 * (1.f / 1024.f);
  float rs = rsqrtf(s2 * (1.f / 1024.f) - mu * mu + 1e-5f);
  float4 xv = *(const float4*)(x + base);
  float4 g1v = *(const float4*)(g1 + t * 4);
  float4 b1v = *(const float4*)(b1 + t * 4);
  float w[4];
  w[0] = xv.x + ((v[0] - mu) * rs * g1v.x + b1v.x);
  w[1] = xv.y + ((v[1] - mu) * rs * g1v.y + b1v.y);
  w[2] = xv.z + ((v[2] - mu) * rs * g1v.z + b1v.z);
  w[3] = xv.w + ((v[3] - mu) * rs * g1v.w + b1v.w);
  s1 = w[0] + w[1] + w[2] + w[3];
  s2 = w[0]*w[0] + w[1]*w[1] + w[2]*w[2] + w[3]*w[3];
  block_sum2(s1, s2, red, t);
  mu = s1 * (1.f / 1024.f);
  rs = rsqrtf(s2 * (1.f / 1024.f) - mu * mu + 1e-5f);
  float4 g2v = *(const float4*)(g2 + t * 4);
  float4 b2v = *(const float4*)(b2 + t * 4);
  U4 ov;
  ov.s[0] = f2bf((w[0] - mu) * rs * g2v.x + b2v.x);
  ov.s[1] = f2bf((w[1] - mu) * rs * g2v.y + b2v.y);
  ov.s[2] = f2bf((w[2] - mu) * rs * g2v.z + b2v.z);
  ov.s[3] = f2bf((w[3] - mu) * rs * g2v.w + b2v.w);
  *(uint2*)(x1 + base) = ov.u;
}

__global__ __launch_bounds__(256) void ln2_k(const u16* __restrict__ y,
                                             const u16* __restrict__ x1,
                                             const float* __restrict__ g,
                                             const float* __restrict__ b,
                                             float* __restrict__ out) {
  __shared__ float red[8];
  int row = blockIdx.x, t = threadIdx.x;
  size_t base = (size_t)row * 1024 + t * 4;
  U4 yv; yv.u = *(const uint2*)(y + base);
  U4 xv; xv.u = *(const uint2*)(x1 + base);
  float w[4];
#pragma unroll
  for (int i = 0; i < 4; i++) w[i] = bf2f(yv.s[i]) + bf2f(xv.s[i]);
  float s1 = w[0] + w[1] + w[2] + w[3];
  float s2 = w[0]*w[0] + w[1]*w[1] + w[2]*w[2] + w[3]*w[3];
  block_sum2(s1, s2, red, t);
  float mu = s1 * (1.f / 1024.f);
  float rs = rsqrtf(s2 * (1.f / 1024.f) - mu * mu + 1e-5f);
  float4 gv = *(const float4*)(g + t * 4);
  float4 bv = *(const float4*)(b + t * 4);
  float4 ov;
  ov.x = (w[0] - mu) * rs * gv.x + bv.x;
  ov.y = (w[1] - mu) * rs * gv.y + bv.y;
  ov.z = (w[2] - mu) * rs * gv.z + bv.z;
  ov.w = (w[3] - mu) * rs * gv.w + bv.w;
  *(float4*)(out + base) = ov;
}

// ---------------------------------------------------------------------------
extern "C" void kernel_launch(void* const* d_in, const int* in_sizes, int n_in,
                              void* d_out, int out_size, void* d_ws, size_t ws_size,
                              hipStream_t stream) {
  (void)in_sizes; (void)n_in; (void)out_size;
  const float* x    = (const float*)d_in[0];
  const int*   mask = (const int*)d_in[1];
  const float* Wq = (const float*)d_in[2];  const float* bq = (const float*)d_in[3];
  const float* Wk = (const float*)d_in[4];  const float* bk = (const float*)d_in[5];
  const float* Wv = (const float*)d_in[6];  const float* bv = (const float*)d_in[7];
  const float* Wo = (const float*)d_in[8];  const float* bo = (const float*)d_in[9];
  const float* temp = (const float*)d_in[10];
  const float* tw   = (const float*)d_in[11];
  const float* gW   = (const float*)d_in[12]; const float* gb  = (const float*)d_in[13];
  const float* lag  = (const float*)d_in[14]; const float* lab = (const float*)d_in[15];
  const float* f1W  = (const float*)d_in[16]; const float* f1b = (const float*)d_in[17];
  const float* f2W  = (const float*)d_in[18]; const float* f2b = (const float*)d_in[19];
  const float* n1g  = (const float*)d_in[20]; const float* n1b = (const float*)d_in[21];
  const float* n2g  = (const float*)d_in[22]; const float* n2b = (const float*)d_in[23];
  float* out = (float*)d_out;

  u16* ws = (u16*)d_ws;
  const size_t MB4 = (size_t)4096 * 1024;
  u16* s0 = ws;                 // WqT  -> VT       -> f1WT
  u16* s1 = ws + 1 * MB4;       // WkT  -> maskbits -> f2WT
  u16* s2 = ws + 2 * MB4;       // WvT  -> CT       -> Y
  u16* s3 = ws + 3 * MB4;       // Q    -> X1
  u16* s4 = ws + 4 * MB4;       // xb   -> WoT
  u16* d0 = (u16*)d_out;        // K    -> PO       -> H(lo, small-ws path)
  u16* d1 = d0 + MB4;           // V    -> H(hi, small-ws path)
  bool bigws = ws_size >= (size_t)9 * 8 * 1024 * 1024;  // 72 MiB
  u16* Hfull = ws + 5 * MB4;

  dim3 blk(256);
  cvt_k<<<dim3(4096), blk, 0, stream>>>(x, s4, 4096 * 1024);
  transpose_cvt3_k<<<dim3(16, 16, 3), blk, 0, stream>>>(Wq, Wk, Wv, s0, s1, s2);
  qkv_gemm<<<dim3(32, 8, 3), blk, 0, stream>>>(s4, s0, s1, s2, s3, d0, d1,
                                               bq, bk, bv, tw);
  vtrans_k<<<dim3(32, 32), blk, 0, stream>>>(d1, s0);
  mb_k<<<dim3(1024), blk, 0, stream>>>(mask, s1);
  transpose_cvt_k<<<dim3(16, 16), blk, 0, stream>>>(Wo, s4, 1024, 1024);
  attn_k<<<dim3(1024), blk, 0, stream>>>(s3, d0, s0, s2, s1, gW, gb, temp);
  gemm_bt<64, 0, 1><<<dim3(64, 8), blk, 0, stream>>>(s2, s4, d0, bo, 4096, 1024, 1024);
  ln1_k<<<dim3(4096), blk, 0, stream>>>(d0, x, lag, lab, n1g, n1b, s3);
  transpose_cvt_k<<<dim3(64, 16), blk, 0, stream>>>(f1W, s0, 1024, 4096);
  transpose_cvt_k<<<dim3(16, 64), blk, 0, stream>>>(f2W, s1, 4096, 1024);
  if (bigws) {
    gemm_bt<128, 2, 0><<<dim3(32, 32), blk, 0, stream>>>(s3, s0, Hfull, f1b,
                                                         4096, 4096, 1024);
    gemm_bt<64, 0, 0><<<dim3(8, 64), blk, 0, stream>>>(Hfull, s1, s2, f2b,
                                                       4096, 1024, 4096);
  } else {
    for (int i = 0; i < 2; i++) {
      const u16* Ai = s3 + (size_t)i * 2048 * 1024;
      u16* Yi = s2 + (size_t)i * 2048 * 1024;
      gemm_bt<128, 2, 0><<<dim3(32, 16), blk, 0, stream>>>(Ai, s0, d0, f1b,
                                                           2048, 4096, 1024);
      gemm_bt<64, 0, 1><<<dim3(32, 8), blk, 0, stream>>>(d0, s1, Yi, f2b,
                                                         2048, 1024, 4096);
    }
  }
  ln2_k<<<dim3(4096), blk, 0, stream>>>(s2, s3, n2g, n2b, out);
}